// Round 2
// baseline (2265.824 us; speedup 1.0000x reference)
//
#include <hip/hip_runtime.h>
#include <cstdio>

// VersorLinear: out[b,s,o,k] = manifold_norm( sum_{i,l} x[b,s,i,l] * weight[o,i,l^k] * sign(l^k,l) )
// == GEMM: C[8192,8192] = A[8192,8192](=x) @ B[8192,8192], B^T built from weight with GP signs.

typedef __attribute__((ext_vector_type(8))) short short8;
typedef __attribute__((ext_vector_type(8))) unsigned short ushort8;
typedef __attribute__((ext_vector_type(4))) float f32x4;

#define MDIM 8192
#define NDIM 8192
#define KDIM 8192

__device__ __forceinline__ unsigned short f2bf(float f) {
  unsigned int u = __float_as_uint(f);
  u += 0x7fffu + ((u >> 16) & 1u);   // round-to-nearest-even
  return (unsigned short)(u >> 16);
}

// sign of e_a * e_b in Cl(4,1): reorder crossings + metric (e5^2 = -1, bit 4)
__device__ __forceinline__ float gpsign(int a, int b) {
  int cross = 0;
#pragma unroll
  for (int i = 0; i < 5; ++i)
    if ((b >> i) & 1) cross += __popc(a >> (i + 1));
  int neg = (cross ^ ((a & b) >> 4)) & 1;
  return neg ? -1.0f : 1.0f;
}

// metric signature: -1 if bit4 set, times -1 if grade*(grade-1)/2 odd
__device__ __forceinline__ float sigk(int k) {
  int g = __popc(k);
  int neg = (((k >> 4) & 1) ^ ((g * (g - 1) / 2) & 1)) & 1;
  return neg ? -1.0f : 1.0f;
}

// ---------------- kernel 1: x fp32 -> A bf16 ----------------
__global__ __launch_bounds__(256) void convert_x(const float* __restrict__ x,
                                                 unsigned short* __restrict__ a) {
  const size_t t = (size_t)blockIdx.x * 256 + threadIdx.x;
  const size_t base = t * 8;
  const float4 v0 = *(const float4*)(x + base);
  const float4 v1 = *(const float4*)(x + base + 4);
  ushort8 r;
  r[0] = f2bf(v0.x); r[1] = f2bf(v0.y); r[2] = f2bf(v0.z); r[3] = f2bf(v0.w);
  r[4] = f2bf(v1.x); r[5] = f2bf(v1.y); r[6] = f2bf(v1.z); r[7] = f2bf(v1.w);
  *(ushort8*)(a + base) = r;
}

// ---------------- kernel 2: build B^T bf16 ----------------
// Bt[(o*32+k)*8192 + (i*32+l)] = weight[o,i,l^k] * gpsign(l^k, l)
__global__ __launch_bounds__(256) void build_bt(const float* __restrict__ w,
                                                unsigned short* __restrict__ bt) {
  const size_t t = (size_t)blockIdx.x * 256 + threadIdx.x;
  const size_t base = t * 8;
  const int c = (int)(base >> 13);       // row index o*32+k
  const int r0 = (int)(base & 8191);     // col index i*32+l, multiple of 8
  const int o = c >> 5, k = c & 31;
  const int i_f = r0 >> 5, l0 = r0 & 31; // l0 in {0,8,16,24}; l0+7 stays in-block
  const float* wrow = w + o * 8192 + i_f * 32;
  ushort8 rv;
#pragma unroll
  for (int e = 0; e < 8; ++e) {
    const int l = l0 + e;
    const int j = l ^ k;
    rv[e] = f2bf(wrow[j] * gpsign(j, l));
  }
  *(ushort8*)(bt + base) = rv;
}

// ---------------- kernel 3: bf16 GEMM 8192^3, C fp32 ----------------
// m97 structure: 128x128 tile, BK=64, 4 waves (2x2), global_load_lds width 16,
// XOR swizzle via pre-swizzled global source (LDS dest stays linear).
__global__ __launch_bounds__(256) void gemm_bf16(const unsigned short* __restrict__ A,
                                                 const unsigned short* __restrict__ Bt,
                                                 float* __restrict__ C) {
  __shared__ unsigned short As[128 * 64];
  __shared__ unsigned short Bs[128 * 64];
  const int tid = threadIdx.x;
  const int lane = tid & 63;
  const int wid = tid >> 6;
  // bijective XCD swizzle: 4096 blocks, 4096 % 8 == 0
  const int orig = blockIdx.x;
  const int wg = (orig & 7) * 512 + (orig >> 3);
  const int bM = wg >> 6;
  const int bN = wg & 63;
  const int wr = wid >> 1, wc = wid & 1;

  // staging geometry: chunk c = wid*256 + q*64 + lane; row = c>>3, slot = c&7
  // row&7 == lane>>3 always, so swizzled slot is per-thread constant
  const int srow = lane >> 3;
  const int xslot = (lane & 7) ^ srow;
  const unsigned short* Abase = A + (size_t)bM * 128 * KDIM + (size_t)xslot * 8;
  const unsigned short* Bbase = Bt + (size_t)bN * 128 * KDIM + (size_t)xslot * 8;

  f32x4 acc[4][4];
#pragma unroll
  for (int m = 0; m < 4; ++m)
#pragma unroll
    for (int n = 0; n < 4; ++n) acc[m][n] = (f32x4)0.0f;

  // fragment read geometry: row&7 == lane&7 in every 16-row band
  const int frow = lane & 15;
  const int fx = (lane & 7) << 4;     // XOR on byte bits 4-6
  const int fko = (lane >> 4) << 3;   // k-byte sub-offset per 16-lane group

  for (int kt = 0; kt < KDIM; kt += 64) {
#pragma unroll
    for (int q = 0; q < 4; ++q) {
      const int row = wid * 32 + q * 8 + srow;
      __builtin_amdgcn_global_load_lds(
          (const __attribute__((address_space(1))) void*)(Abase + (size_t)row * KDIM + kt),
          (__attribute__((address_space(3))) void*)((char*)As + (wid * 256 + q * 64) * 16),
          16, 0, 0);
      __builtin_amdgcn_global_load_lds(
          (const __attribute__((address_space(1))) void*)(Bbase + (size_t)row * KDIM + kt),
          (__attribute__((address_space(3))) void*)((char*)Bs + (wid * 256 + q * 64) * 16),
          16, 0, 0);
    }
    __syncthreads();
#pragma unroll
    for (int kk = 0; kk < 2; ++kk) {
      short8 af[4], bf[4];
#pragma unroll
      for (int m = 0; m < 4; ++m) {
        const int row = wr * 64 + m * 16 + frow;
        const int kb = kk * 64 + fko;
        union { short8 v; uint2 u[2]; } u;
        u.u[0] = *(const uint2*)((const char*)As + row * 128 + ((kb) ^ fx));
        u.u[1] = *(const uint2*)((const char*)As + row * 128 + ((kb + 32) ^ fx));
        af[m] = u.v;
      }
#pragma unroll
      for (int n = 0; n < 4; ++n) {
        const int row = wc * 64 + n * 16 + frow;
        const int kb = kk * 64 + fko;
        union { short8 v; uint2 u[2]; } u;
        u.u[0] = *(const uint2*)((const char*)Bs + row * 128 + ((kb) ^ fx));
        u.u[1] = *(const uint2*)((const char*)Bs + row * 128 + ((kb + 32) ^ fx));
        bf[n] = u.v;
      }
#pragma unroll
      for (int m = 0; m < 4; ++m)
#pragma unroll
        for (int n = 0; n < 4; ++n)
          acc[m][n] = __builtin_amdgcn_mfma_f32_16x16x32_bf16(af[m], bf[n], acc[m][n], 0, 0, 0);
    }
    __syncthreads();
  }

  // C/D layout (HW-verified m89/m91): col = lane&15, row = (lane>>4)*4 + reg
  const int ccol = bN * 128 + wc * 64 + (lane & 15);
  const int crow = bM * 128 + wr * 64 + ((lane >> 4) << 2);
#pragma unroll
  for (int m = 0; m < 4; ++m)
#pragma unroll
    for (int n = 0; n < 4; ++n)
#pragma unroll
      for (int r = 0; r < 4; ++r)
        C[(size_t)(crow + m * 16 + r) * NDIM + (ccol + n * 16)] = acc[m][n][r];
}

// ---------------- kernel 4: manifold normalization in-place ----------------
// 8 lanes per 32-component group; float4 per lane; shfl_xor reduce over 8 lanes
__global__ __launch_bounds__(256) void norm_kernel(float* __restrict__ out) {
  const size_t t = (size_t)blockIdx.x * 256 + threadIdx.x;
  const size_t base = t * 4;
  float4 v = *(const float4*)(out + base);
  const int k0 = ((int)t & 7) * 4;
  float s2 = v.x * v.x + v.y * v.y + v.z * v.z + v.w * v.w;
  float ss = v.x * v.x * sigk(k0) + v.y * v.y * sigk(k0 + 1) +
             v.z * v.z * sigk(k0 + 2) + v.w * v.w * sigk(k0 + 3);
#pragma unroll
  for (int m = 1; m <= 4; m <<= 1) {
    s2 += __shfl_xor(s2, m);
    ss += __shfl_xor(ss, m);
  }
  float denom = fmaxf(sqrtf(fabsf(ss) + 1e-6f), sqrtf(s2) * 0.25f + 1e-6f);
  denom = fmaxf(denom, 1.0f);
  const float inv = 1.0f / denom;
  v.x *= inv; v.y *= inv; v.z *= inv; v.w *= inv;
  *(float4*)(out + base) = v;
}

extern "C" void kernel_launch(void* const* d_in, const int* in_sizes, int n_in,
                              void* d_out, int out_size, void* d_ws, size_t ws_size,
                              hipStream_t stream) {
  const float* x = (const float*)d_in[0];
  const float* w = (const float*)d_in[1];
  float* out = (float*)d_out;

  const size_t NELEM = (size_t)MDIM * KDIM;     // 67,108,864
  const size_t need = NELEM * 2 * 2;            // A bf16 + B^T bf16 = 256 MB
  if (ws_size < need) {
    fprintf(stderr, "VersorLinear: ws_size=%zu < needed %zu — cannot run\n", ws_size, need);
    return;
  }
  unsigned short* Abf = (unsigned short*)d_ws;
  unsigned short* Bbf = Abf + NELEM;

  convert_x<<<dim3(32768), dim3(256), 0, stream>>>(x, Abf);      // 67M elems / 8 per thread
  build_bt<<<dim3(32768), dim3(256), 0, stream>>>(w, Bbf);       // 67M elems / 8 per thread
  gemm_bf16<<<dim3(4096), dim3(256), 0, stream>>>(Abf, Bbf, out);
  norm_kernel<<<dim3(65536), dim3(256), 0, stream>>>(out);       // 2M groups * 8 lanes
}

// Round 5
// 1569.473 us; speedup vs baseline: 1.4437x; 1.4437x over previous
//
#include <hip/hip_runtime.h>
#include <cstdio>

// VersorLinear: out[b,s,o,k] = manifold_norm( sum_{i,l} x[b,s,i,l] * weight[o,i,l^k] * sign(l^k,l) )
// == GEMM: C[8192,8192] = A(=x) @ B, Bt built from weight with GP signs.
// GEMM = m201-style 256x256 8-phase schedule (T1+T2+T3+T4+T5).

typedef __attribute__((ext_vector_type(8))) short short8;
typedef __attribute__((ext_vector_type(8))) unsigned short ushort8;
typedef __attribute__((ext_vector_type(4))) float f32x4;

#define MDIM 8192
#define NDIM 8192
#define KDIM 8192
#define NT   128   // K-tiles of 64
#define NITER 64   // 2 tiles per iteration

__device__ __forceinline__ unsigned short f2bf(float f) {
  unsigned int u = __float_as_uint(f);
  u += 0x7fffu + ((u >> 16) & 1u);   // RNE
  return (unsigned short)(u >> 16);
}

__device__ __forceinline__ float gpsign(int a, int b) {
  int cross = 0;
#pragma unroll
  for (int i = 0; i < 5; ++i)
    if ((b >> i) & 1) cross += __popc(a >> (i + 1));
  int neg = (cross ^ ((a & b) >> 4)) & 1;
  return neg ? -1.0f : 1.0f;
}

__device__ __forceinline__ float sigk(int k) {
  int g = __popc(k);
  int neg = (((k >> 4) & 1) ^ ((g * (g - 1) / 2) & 1)) & 1;
  return neg ? -1.0f : 1.0f;
}

// ---------------- kernel 1: x fp32 -> A bf16 ----------------
__global__ __launch_bounds__(256) void convert_x(const float* __restrict__ x,
                                                 unsigned short* __restrict__ a) {
  const size_t t = (size_t)blockIdx.x * 256 + threadIdx.x;
  const size_t base = t * 8;
  const float4 v0 = *(const float4*)(x + base);
  const float4 v1 = *(const float4*)(x + base + 4);
  ushort8 r;
  r[0] = f2bf(v0.x); r[1] = f2bf(v0.y); r[2] = f2bf(v0.z); r[3] = f2bf(v0.w);
  r[4] = f2bf(v1.x); r[5] = f2bf(v1.y); r[6] = f2bf(v1.z); r[7] = f2bf(v1.w);
  *(ushort8*)(a + base) = r;
}

// ---------------- kernel 2: build B^T bf16 ----------------
__global__ __launch_bounds__(256) void build_bt(const float* __restrict__ w,
                                                unsigned short* __restrict__ bt) {
  const size_t t = (size_t)blockIdx.x * 256 + threadIdx.x;
  const size_t base = t * 8;
  const int c = (int)(base >> 13);
  const int r0 = (int)(base & 8191);
  const int o = c >> 5, k = c & 31;
  const int i_f = r0 >> 5, l0 = r0 & 31;
  const float* wrow = w + o * 8192 + i_f * 32;
  ushort8 rv;
#pragma unroll
  for (int e = 0; e < 8; ++e) {
    const int l = l0 + e;
    const int j = l ^ k;
    rv[e] = f2bf(wrow[j] * gpsign(j, l));
  }
  *(ushort8*)(bt + base) = rv;
}

// ---------------- kernel 3: 256x256 8-phase bf16 GEMM ----------------
template <int BUF, int QM, int QN, bool RA, bool RB, bool CKPT, class Stage>
__device__ __forceinline__ void phase_fn(const char* sA, const char* sB,
                                         int ra0, int rb0, int e0,
                                         short8 (&af)[2][2], short8 (&bf)[4][2],
                                         f32x4 (&acc)[2][2][2][4], Stage stage) {
  if (RA) {
#pragma unroll
    for (int m = 0; m < 2; ++m)
#pragma unroll
      for (int kk = 0; kk < 2; ++kk)
        af[m][kk] = *(const short8*)(sA + (BUF * 2 + QM) * 16384 +
                                     (ra0 + m * 16) * 128 + (e0 ^ (kk * 64)));
  }
  if (RB) {
#pragma unroll
    for (int n = 0; n < 4; ++n)
#pragma unroll
      for (int kk = 0; kk < 2; ++kk)
        bf[n][kk] = *(const short8*)(sB + (BUF * 2 + QN) * 16384 +
                                     (rb0 + n * 16) * 128 + (e0 ^ (kk * 64)));
  }
  stage();
  __builtin_amdgcn_s_barrier();
  asm volatile("s_waitcnt lgkmcnt(0)" ::: "memory");
  __builtin_amdgcn_sched_barrier(0);
  __builtin_amdgcn_s_setprio(1);
#pragma unroll
  for (int kk = 0; kk < 2; ++kk)
#pragma unroll
    for (int m = 0; m < 2; ++m)
#pragma unroll
      for (int n = 0; n < 4; ++n)
        acc[QM][QN][m][n] = __builtin_amdgcn_mfma_f32_16x16x32_bf16(
            af[m][kk], bf[n][kk], acc[QM][QN][m][n], 0, 0, 0);
  __builtin_amdgcn_s_setprio(0);
  if (CKPT) asm volatile("s_waitcnt vmcnt(6)" ::: "memory");
  __builtin_amdgcn_s_barrier();
}

__global__ __launch_bounds__(512, 2) void gemm256(const unsigned short* __restrict__ A,
                                                  const unsigned short* __restrict__ Bt,
                                                  float* __restrict__ C) {
  extern __shared__ char smem[];        // 128 KiB: A halves [0,64K), B halves [64K,128K)
  const int tid = threadIdx.x;
  const int lane = tid & 63;
  const int wid = tid >> 6;

  // bijective XCD swizzle (1024 blocks, 1024 % 8 == 0)
  const int orig = blockIdx.x;
  const int wg = (orig & 7) * 128 + (orig >> 3);
  const int bM = wg >> 5, bN = wg & 31;

  // ds-read per-thread constants
  const int e0 = (((lane >> 4) ^ (lane & 7)) << 4);
  const int ra0 = ((wid >> 1) << 5) + (lane & 15);
  const int rb0 = ((wid & 1) << 6) + (lane & 15);
  const char* sA = smem;
  const char* sB = smem + 65536;

  // staging per-thread constants: chunk c = q*512+tid; row=c>>3, lds slot=c&7,
  // global slot = (c&7) ^ (row&7) = (lane&7) ^ (lane>>3)
  const int sslot = (lane & 7) ^ (lane >> 3);
  const int srow = tid >> 3;            // + q*64

  auto stageA = [&](int tile, int half) {
    const int t = tile < NT ? tile : NT - 1;
    const int bufh = ((t & 1) * 2 + half) * 16384;
    const int kt = t * 64;
#pragma unroll
    for (int q = 0; q < 2; ++q) {
      const int row = q * 64 + srow;
      const unsigned short* src =
          A + (size_t)(bM * 256 + half * 128 + row) * KDIM + kt + sslot * 8;
      __builtin_amdgcn_global_load_lds(
          (const __attribute__((address_space(1))) void*)src,
          (__attribute__((address_space(3))) void*)(smem + bufh + (q * 512 + tid) * 16),
          16, 0, 0);
    }
  };
  auto stageB = [&](int tile, int half) {
    const int t = tile < NT ? tile : NT - 1;
    const int bufh = 65536 + ((t & 1) * 2 + half) * 16384;
    const int kt = t * 64;
#pragma unroll
    for (int q = 0; q < 2; ++q) {
      const int row = q * 64 + srow;
      const unsigned short* src =
          Bt + (size_t)(bN * 256 + half * 128 + row) * KDIM + kt + sslot * 8;
      __builtin_amdgcn_global_load_lds(
          (const __attribute__((address_space(1))) void*)src,
          (__attribute__((address_space(3))) void*)(smem + bufh + (q * 512 + tid) * 16),
          16, 0, 0);
    }
  };

  // prologue: t0 {Ah0,Bh1,Ah1,Bh0} + t1 {Ah0,Bh1,Ah1}; wait so t0 resident (6 left)
  stageA(0, 0); stageB(0, 1); stageA(0, 1); stageB(0, 0);
  stageA(1, 0); stageB(1, 1); stageA(1, 1);

  f32x4 acc[2][2][2][4];
#pragma unroll
  for (int a = 0; a < 2; ++a)
#pragma unroll
    for (int b = 0; b < 2; ++b)
#pragma unroll
      for (int m = 0; m < 2; ++m)
#pragma unroll
        for (int n = 0; n < 4; ++n) acc[a][b][m][n] = (f32x4)0.0f;

  short8 af[2][2], bf[4][2];

  asm volatile("s_waitcnt vmcnt(6)" ::: "memory");
  __builtin_amdgcn_s_barrier();

  for (int it = 0; it < NITER; ++it) {
    const int t1v = 2 * it + 1;
    const int t2 = 2 * it + 2, t3 = 2 * it + 3;
    // tile 2it in buf0: quads (0,0) (0,1) (1,1) (1,0)
    phase_fn<0, 0, 0, true,  true,  false>(sA, sB, ra0, rb0, e0, af, bf, acc,
                                           [&] { stageB(t1v, 0); });
    phase_fn<0, 0, 1, false, true,  false>(sA, sB, ra0, rb0, e0, af, bf, acc,
                                           [&] { stageA(t2, 0); });
    phase_fn<0, 1, 1, true,  false, false>(sA, sB, ra0, rb0, e0, af, bf, acc,
                                           [&] { stageB(t2, 1); });
    phase_fn<0, 1, 0, false, true,  true >(sA, sB, ra0, rb0, e0, af, bf, acc,
                                           [&] { stageA(t2, 1); });
    // tile 2it+1 in buf1
    phase_fn<1, 0, 0, true,  true,  false>(sA, sB, ra0, rb0, e0, af, bf, acc,
                                           [&] { stageB(t2, 0); });
    phase_fn<1, 0, 1, false, true,  false>(sA, sB, ra0, rb0, e0, af, bf, acc,
                                           [&] { stageA(t3, 0); });
    phase_fn<1, 1, 1, true,  false, false>(sA, sB, ra0, rb0, e0, af, bf, acc,
                                           [&] { stageB(t3, 1); });
    phase_fn<1, 1, 0, false, true,  true >(sA, sB, ra0, rb0, e0, af, bf, acc,
                                           [&] { stageA(t3, 1); });
  }

  // epilogue: C/D layout col=lane&15, row=(lane>>4)*4+r (HW-verified)
  const int crow0 = bM * 256 + ((wid >> 1) << 5) + ((lane >> 4) << 2);
  const int ccol0 = bN * 256 + ((wid & 1) << 6) + (lane & 15);
#pragma unroll
  for (int qm = 0; qm < 2; ++qm)
#pragma unroll
    for (int qn = 0; qn < 2; ++qn)
#pragma unroll
      for (int m = 0; m < 2; ++m)
#pragma unroll
        for (int n = 0; n < 4; ++n)
#pragma unroll
          for (int r = 0; r < 4; ++r)
            C[(size_t)(crow0 + qm * 128 + m * 16 + r) * NDIM +
              (ccol0 + qn * 128 + n * 16)] = acc[qm][qn][m][n][r];
}

// ---------------- kernel 4: manifold normalization in-place ----------------
__global__ __launch_bounds__(256) void norm_kernel(float* __restrict__ out) {
  const size_t t = (size_t)blockIdx.x * 256 + threadIdx.x;
  const size_t base = t * 4;
  float4 v = *(const float4*)(out + base);
  const int k0 = ((int)t & 7) * 4;
  float s2 = v.x * v.x + v.y * v.y + v.z * v.z + v.w * v.w;
  float ss = v.x * v.x * sigk(k0) + v.y * v.y * sigk(k0 + 1) +
             v.z * v.z * sigk(k0 + 2) + v.w * v.w * sigk(k0 + 3);
#pragma unroll
  for (int m = 1; m <= 4; m <<= 1) {
    s2 += __shfl_xor(s2, m);
    ss += __shfl_xor(ss, m);
  }
  float denom = fmaxf(sqrtf(fabsf(ss) + 1e-6f), sqrtf(s2) * 0.25f + 1e-6f);
  denom = fmaxf(denom, 1.0f);
  const float inv = 1.0f / denom;
  v.x *= inv; v.y *= inv; v.z *= inv; v.w *= inv;
  *(float4*)(out + base) = v;
}

extern "C" void kernel_launch(void* const* d_in, const int* in_sizes, int n_in,
                              void* d_out, int out_size, void* d_ws, size_t ws_size,
                              hipStream_t stream) {
  const float* x = (const float*)d_in[0];
  const float* w = (const float*)d_in[1];
  float* out = (float*)d_out;

  const size_t NELEM = (size_t)MDIM * KDIM;
  const size_t need = NELEM * 2 * 2;   // A bf16 + B^T bf16 = 256 MB
  if (ws_size < need) {
    fprintf(stderr, "VersorLinear: ws_size=%zu < needed %zu\n", ws_size, need);
    return;
  }
  unsigned short* Abf = (unsigned short*)d_ws;
  unsigned short* Bbf = Abf + NELEM;

  convert_x<<<dim3(32768), dim3(256), 0, stream>>>(x, Abf);
  build_bt<<<dim3(32768), dim3(256), 0, stream>>>(w, Bbf);
  gemm256<<<dim3(1024), dim3(512), 131072, stream>>>(Abf, Bbf, out);
  norm_kernel<<<dim3(65536), dim3(256), 0, stream>>>(out);
}